// Round 21
// baseline (5762.593 us; speedup 1.0000x reference)
//
#include <hip/hip_runtime.h>

#define L_DIM 16
#define N_DIM 200000
#define M_DIM 100000
#define F_DIM 7
#define H_DIM 64
#define NTILE (M_DIM / 32)   // 3125
#define NWAVE 1563           // 2 tiles per wave: v and v+NWAVE

typedef _Float16 f16;
typedef __attribute__((ext_vector_type(4))) _Float16 f16x4;
typedef __attribute__((ext_vector_type(8))) _Float16 f16x8;
typedef __attribute__((ext_vector_type(4))) float f32x4;

#define MFMA(a,b,c) __builtin_amdgcn_mfma_f32_16x16x32_f16((a),(b),(c),0,0,0)

// pack sizes (f16 elements)
#define NR_PK (192 * 192)
#define NH_PK (64 * 192)
#define NZ_PK (256 * 256)

__device__ __forceinline__ float tanh_(float x) {
    float e = __expf(2.f * x);
    return 1.f - 2.f / (e + 1.f);
}

// ---------------------------------------------------------------------------
// u = tanh(contents_l @ Wu.T + bu) -> out (N,64). 4 outputs/thread, float4 store.
// ---------------------------------------------------------------------------
__global__ __launch_bounds__(256) void u_kernel(const float* __restrict__ contents_l,
                                                const float* __restrict__ Wu,
                                                const float* __restrict__ bu,
                                                float* __restrict__ out) {
    __shared__ float sWu[H_DIM * F_DIM];
    __shared__ float sbu[H_DIM];
    int t = threadIdx.x;
    for (int idx = t; idx < H_DIM * F_DIM; idx += 256) sWu[idx] = Wu[idx];
    if (t < H_DIM) sbu[t] = bu[t];
    __syncthreads();

    int gid = blockIdx.x * 256 + t;
    int i = gid >> 4;
    int h0 = (gid & 15) * 4;
    if (i >= N_DIM) return;
    const float* c = contents_l + (size_t)i * F_DIM;
    float cv[F_DIM];
#pragma unroll
    for (int f = 0; f < F_DIM; ++f) cv[f] = c[f];
    float4 o;
#pragma unroll
    for (int q = 0; q < 4; ++q) {
        float acc = sbu[h0 + q];
#pragma unroll
        for (int f = 0; f < F_DIM; ++f) acc = fmaf(cv[f], sWu[(h0 + q) * F_DIM + f], acc);
        ((float*)&o)[q] = tanh_(acc);
    }
    *(float4*)(out + (size_t)i * H_DIM + h0) = o;
}

// ---------------------------------------------------------------------------
// Pack weights into MFMA fragment order with the custom2 k-rule (as R8):
//   koff(g4,j) = (j<4) ? 4*g4+j : 16+4*g4+(j-4)
//   value = W[16*t16 + (lane&15)][32*ks + koff(lane>>4, j)]
// ---------------------------------------------------------------------------
__global__ void prep_pack(const float* __restrict__ Wr, const float* __restrict__ Wh,
                          const float* __restrict__ Wz, f16* __restrict__ out) {
    int idx = blockIdx.x * 256 + threadIdx.x;
    if (idx >= NR_PK + NH_PK + NZ_PK) return;
    int e, Kdim, KS;
    const float* W;
    f16* dst;
    if (idx < NR_PK) { e = idx; W = Wr; Kdim = 192; KS = 6; dst = out; }
    else if (idx < NR_PK + NH_PK) { e = idx - NR_PK; W = Wh; Kdim = 192; KS = 6; dst = out + NR_PK; }
    else { e = idx - NR_PK - NH_PK; W = Wz; Kdim = 256; KS = 8; dst = out + NR_PK + NH_PK; }
    int j = e & 7;
    int l = (e >> 3) & 63;
    int tile = e >> 9;
    int ks = tile % KS;
    int t16 = tile / KS;
    int g4 = l >> 4;
    int koff = (j < 4) ? (4 * g4 + j) : (16 + 4 * g4 + (j - 4));
    int k = ks * 32 + koff;
    int n = t16 * 16 + (l & 15);
    dst[e] = (f16)W[n * Kdim + k];
}

// load an A/B fragment in custom2 layout from an fp32 row pointer (32-col slice)
__device__ __forceinline__ f16x8 frag2(const float* __restrict__ p, int g4) {
    float4 a = *(const float4*)(p + 4 * g4);
    float4 b = *(const float4*)(p + 16 + 4 * g4);
    f16x8 h = {(f16)a.x, (f16)a.y, (f16)a.z, (f16)a.w,
               (f16)b.x, (f16)b.y, (f16)b.z, (f16)b.w};
    return h;
}

// ---------------------------------------------------------------------------
// One 32-row tile (R20 body verbatim). __forceinline__ so two sequential
// calls become straight-line duplication (loops/noinline-calls proved to
// spill: R11/R12/R14). aR[1] hand-spilled to LDS Lr; hL/hR/hH stashed in
// LDS for the epilogue.
// ---------------------------------------------------------------------------
__device__ __forceinline__ void process_tile(
    const float* __restrict__ embP,
    float* __restrict__ embC,
    const int* __restrict__ chl,
    const f16x8* __restrict__ WrP,
    const f16x8* __restrict__ WhP,
    const f16x8* __restrict__ WzP,
    const float* __restrict__ br,
    const float* __restrict__ bh,
    const float* __restrict__ bz,
    f16 (*LgL)[68], f16 (*LgR)[68], f16 (*Lh)[72], f16x8 (*Lr)[64],
    int wbase, int l, int l15, int g4)
{
    const f32x4 zz = {0.f, 0.f, 0.f, 0.f};

    // ---- gather: A-fragments of [hL|hR|u]; stash hL/hR to LDS ----
    f16x8 aH[2][6];
#pragma unroll
    for (int rg = 0; rg < 2; ++rg) {
        int i = wbase + rg * 16 + l15;
        int iL = chl[2 * i], iR = chl[2 * i + 1];
        const float* pL = embP + (size_t)iL * 64;
        const float* pR = embP + (size_t)iR * 64;
        const float* pU = embC + (size_t)i * 64;
        aH[rg][0] = frag2(pL, g4);      aH[rg][1] = frag2(pL + 32, g4);
        aH[rg][2] = frag2(pR, g4);      aH[rg][3] = frag2(pR + 32, g4);
        aH[rg][4] = frag2(pU, g4);      aH[rg][5] = frag2(pU + 32, g4);

        int row = rg * 16 + l15;
        // custom2 inverse: elems 0..3 -> cols base+4g4, elems 4..7 -> base+16+4g4
        f16x8 hA = aH[rg][0], hB = aH[rg][1];
        *(f16x4*)&LgL[row][4 * g4]      = (f16x4){hA[0], hA[1], hA[2], hA[3]};
        *(f16x4*)&LgL[row][16 + 4 * g4] = (f16x4){hA[4], hA[5], hA[6], hA[7]};
        *(f16x4*)&LgL[row][32 + 4 * g4] = (f16x4){hB[0], hB[1], hB[2], hB[3]};
        *(f16x4*)&LgL[row][48 + 4 * g4] = (f16x4){hB[4], hB[5], hB[6], hB[7]};
        f16x8 rA = aH[rg][2], rB = aH[rg][3];
        *(f16x4*)&LgR[row][4 * g4]      = (f16x4){rA[0], rA[1], rA[2], rA[3]};
        *(f16x4*)&LgR[row][16 + 4 * g4] = (f16x4){rA[4], rA[5], rA[6], rA[7]};
        *(f16x4*)&LgR[row][32 + 4 * g4] = (f16x4){rB[0], rB[1], rB[2], rB[3]};
        *(f16x4*)&LgR[row][48 + 4 * g4] = (f16x4){rB[4], rB[5], rB[6], rB[7]};
    }

    // ---- GEMM1 (transposed): aR = sigmoid(Wr @ hhu^T + br) * aH ----
    // aR[0][*] stays in regs; aR[1][*] streamed to LDS (Lr).
    f16x8 aR0[6];
#pragma unroll
    for (int kr = 0; kr < 6; ++kr) {
        f16x8 A[6];
#pragma unroll
        for (int ks = 0; ks < 6; ++ks) A[ks] = WrP[((2 * kr) * 6 + ks) * 64 + l];
        f32x4 c00 = zz, c01 = zz;
#pragma unroll
        for (int ks = 0; ks < 6; ++ks) {
            c00 = MFMA(A[ks], aH[0][ks], c00);
            c01 = MFMA(A[ks], aH[1][ks], c01);
        }
#pragma unroll
        for (int ks = 0; ks < 6; ++ks) A[ks] = WrP[((2 * kr + 1) * 6 + ks) * 64 + l];
        f32x4 c10 = zz, c11 = zz;
#pragma unroll
        for (int ks = 0; ks < 6; ++ks) {
            c10 = MFMA(A[ks], aH[0][ks], c10);
            c11 = MFMA(A[ks], aH[1][ks], c11);
        }
        float4 bA = *(const float4*)(br + 32 * kr + 4 * g4);
        float4 bB = *(const float4*)(br + 32 * kr + 16 + 4 * g4);
#pragma unroll
        for (int rg = 0; rg < 2; ++rg) {
            f32x4 clo = (rg == 0) ? c00 : c01;
            f32x4 chi = (rg == 0) ? c10 : c11;
            f16x8 h = aH[rg][kr];
            float s0 = 1.f / (1.f + __expf(-(clo[0] + bA.x)));
            float s1 = 1.f / (1.f + __expf(-(clo[1] + bA.y)));
            float s2 = 1.f / (1.f + __expf(-(clo[2] + bA.z)));
            float s3 = 1.f / (1.f + __expf(-(clo[3] + bA.w)));
            float s4 = 1.f / (1.f + __expf(-(chi[0] + bB.x)));
            float s5 = 1.f / (1.f + __expf(-(chi[1] + bB.y)));
            float s6 = 1.f / (1.f + __expf(-(chi[2] + bB.z)));
            float s7 = 1.f / (1.f + __expf(-(chi[3] + bB.w)));
            f16x8 o = {(f16)(s0 * (float)h[0]), (f16)(s1 * (float)h[1]),
                       (f16)(s2 * (float)h[2]), (f16)(s3 * (float)h[3]),
                       (f16)(s4 * (float)h[4]), (f16)(s5 * (float)h[5]),
                       (f16)(s6 * (float)h[6]), (f16)(s7 * (float)h[7])};
            if (rg == 0) aR0[kr] = o;
            else         Lr[kr][l] = o;         // LDS spill (wave-local)
        }
    }

    // ---- GEMM2 (transposed ONLY): ht[rg][t4] = Wh_t4 @ rh^T ----
    f32x4 ht[2][4];
#pragma unroll
    for (int rg = 0; rg < 2; ++rg)
#pragma unroll
        for (int t4 = 0; t4 < 4; ++t4) ht[rg][t4] = zz;
#pragma unroll
    for (int ks = 0; ks < 6; ++ks) {
        f16x8 Wt[4];
#pragma unroll
        for (int t4 = 0; t4 < 4; ++t4) Wt[t4] = WhP[(t4 * 6 + ks) * 64 + l];
        f16x8 a1 = Lr[ks][l];                   // LDS reload (wave-local)
#pragma unroll
        for (int t4 = 0; t4 < 4; ++t4) {
            ht[0][t4] = MFMA(Wt[t4], aR0[ks], ht[0][t4]);
            ht[1][t4] = MFMA(Wt[t4], a1, ht[1][t4]);
        }
    }

    // ---- tanh; build aZ in regs; stash hH to Lh for the epilogue ----
    f16x8 aZ[2][2];
    {
        float4 bh0 = *(const float4*)(bh + 4 * g4);
        float4 bh1 = *(const float4*)(bh + 16 + 4 * g4);
        float4 bh2 = *(const float4*)(bh + 32 + 4 * g4);
        float4 bh3 = *(const float4*)(bh + 48 + 4 * g4);
#pragma unroll
        for (int rg = 0; rg < 2; ++rg) {
            f16x4 th0 = {(f16)tanh_(ht[rg][0][0] + bh0.x), (f16)tanh_(ht[rg][0][1] + bh0.y),
                         (f16)tanh_(ht[rg][0][2] + bh0.z), (f16)tanh_(ht[rg][0][3] + bh0.w)};
            f16x4 th1 = {(f16)tanh_(ht[rg][1][0] + bh1.x), (f16)tanh_(ht[rg][1][1] + bh1.y),
                         (f16)tanh_(ht[rg][1][2] + bh1.z), (f16)tanh_(ht[rg][1][3] + bh1.w)};
            f16x4 th2 = {(f16)tanh_(ht[rg][2][0] + bh2.x), (f16)tanh_(ht[rg][2][1] + bh2.y),
                         (f16)tanh_(ht[rg][2][2] + bh2.z), (f16)tanh_(ht[rg][2][3] + bh2.w)};
            f16x4 th3 = {(f16)tanh_(ht[rg][3][0] + bh3.x), (f16)tanh_(ht[rg][3][1] + bh3.y),
                         (f16)tanh_(ht[rg][3][2] + bh3.z), (f16)tanh_(ht[rg][3][3] + bh3.w)};
            int row = rg * 16 + l15;
            *(f16x4*)&Lh[row][4 * g4]      = th0;
            *(f16x4*)&Lh[row][16 + 4 * g4] = th1;
            *(f16x4*)&Lh[row][32 + 4 * g4] = th2;
            *(f16x4*)&Lh[row][48 + 4 * g4] = th3;
            aZ[rg][0] = (f16x8){th0[0], th0[1], th0[2], th0[3],
                                th1[0], th1[1], th1[2], th1[3]};
            aZ[rg][1] = (f16x8){th2[0], th2[1], th2[2], th2[3],
                                th3[0], th3[1], th3[2], th3[3]};
        }
    }

    // ---- GEMM3 (normal) + fused epilogue per 16-col group T ----
#pragma unroll
    for (int T = 0; T < 4; ++T) {
        f32x4 ac[2][4];
#pragma unroll
        for (int g = 0; g < 4; ++g) {
            int nt = g * 4 + T;
            f16x8 bb[8];
#pragma unroll
            for (int ks = 0; ks < 8; ++ks) bb[ks] = WzP[(nt * 8 + ks) * 64 + l];
#pragma unroll
            for (int rg = 0; rg < 2; ++rg) {
                f32x4 a = zz;
                a = MFMA(aZ[rg][0], bb[0], a);
                a = MFMA(aZ[rg][1], bb[1], a);
#pragma unroll
                for (int ks = 2; ks < 8; ++ks) a = MFMA(aH[rg][ks - 2], bb[ks], a);
                ac[rg][g] = a;
            }
        }
        int col = T * 16 + l15;
        float b0 = bz[col], b1 = bz[64 + col], b2 = bz[128 + col], b3 = bz[192 + col];
#pragma unroll
        for (int rg = 0; rg < 2; ++rg)
#pragma unroll
            for (int r = 0; r < 4; ++r) {
                int row = rg * 16 + 4 * g4 + r;
                int i = wbase + row;
                float z0 = ac[rg][0][r] + b0;
                float z1 = ac[rg][1][r] + b1;
                float z2 = ac[rg][2][r] + b2;
                float z3 = ac[rg][3][r] + b3;
                float mx = fmaxf(fmaxf(z0, z1), fmaxf(z2, z3));
                float e0 = __expf(z0 - mx), e1 = __expf(z1 - mx);
                float e2 = __expf(z2 - mx), e3 = __expf(z3 - mx);
                float rs = __frcp_rn(e0 + e1 + e2 + e3);
                float hHv = (float)Lh[row][col];
                float hLv = (float)LgL[row][col];
                float hRv = (float)LgR[row][col];
                float uv  = embC[(size_t)i * 64 + col];     // read-before-write
                embC[(size_t)i * 64 + col] =
                    (e0 * hHv + e1 * hLv + e2 * hRv + e3 * uv) * rs;
            }
    }
}

// ---------------------------------------------------------------------------
// Fused step: 256 thr = 4 independent waves; wave wv = blockIdx*4+w does
// TWO tiles {wv, wv+NWAVE} as two straight-line inlined calls (no loop).
// 1563 waves = 6.1/CU <= 8 resident -> single dispatch round, no tail.
// ---------------------------------------------------------------------------
__global__ __launch_bounds__(256, 2) void step_kernel(
    const float* __restrict__ embP,
    float* __restrict__ embC,
    const int* __restrict__ chl,
    const f16x8* __restrict__ WrP,
    const f16x8* __restrict__ WhP,
    const f16x8* __restrict__ WzP,
    const float* __restrict__ br,
    const float* __restrict__ bh,
    const float* __restrict__ bz)
{
    __shared__ f16 LgL[4][32][68];   // 17408 B: hL (natural col order)
    __shared__ f16 LgR[4][32][68];   // 17408 B: hR
    __shared__ f16 Lh[4][32][72];    // 18432 B: hH
    __shared__ f16x8 Lr[4][6][64];   // 24576 B: aR[rg=1] spill, lane-contiguous

    const int w = threadIdx.x >> 6;
    const int wv = blockIdx.x * 4 + w;
    if (wv >= NWAVE) return;
    const int l = threadIdx.x & 63;
    const int l15 = l & 15;
    const int g4 = l >> 4;

    process_tile(embP, embC, chl, WrP, WhP, WzP, br, bh, bz,
                 LgL[w], LgR[w], Lh[w], Lr[w], wv * 32, l, l15, g4);
    int tile2 = wv + NWAVE;
    if (tile2 < NTILE)
        process_tile(embP, embC, chl, WrP, WhP, WzP, br, bh, bz,
                     LgL[w], LgR[w], Lh[w], Lr[w], tile2 * 32, l, l15, g4);
}

// ---------------------------------------------------------------------------
extern "C" void kernel_launch(void* const* d_in, const int* in_sizes, int n_in,
                              void* d_out, int out_size, void* d_ws, size_t ws_size,
                              hipStream_t stream) {
    const float* contents = (const float*)d_in[0];
    const int*   children = (const int*)d_in[1];
    const float* Wu = (const float*)d_in[2];
    const float* bu = (const float*)d_in[3];
    const float* Wh = (const float*)d_in[4];
    const float* bh = (const float*)d_in[5];
    const float* Wz = (const float*)d_in[6];
    const float* bz = (const float*)d_in[7];
    const float* Wr = (const float*)d_in[8];
    const float* br = (const float*)d_in[9];
    float* out = (float*)d_out;
    float* ws  = (float*)d_ws;

    float* embEven = ws;                             // N*64 fp32
    f16*   pack    = (f16*)(ws + (size_t)N_DIM * H_DIM);
    const f16x8* WrP = (const f16x8*)pack;
    const f16x8* WhP = (const f16x8*)(pack + NR_PK);
    const f16x8* WzP = (const f16x8*)(pack + NR_PK + NH_PK);

    const int NPK = NR_PK + NH_PK + NZ_PK;
    prep_pack<<<(NPK + 255) / 256, 256, 0, stream>>>(Wr, Wh, Wz, pack);

    int ublocks = (N_DIM * 16 + 255) / 256;   // 12500
    int sblocks = (NWAVE + 3) / 4;            // 391 wgs x 4 waves

    u_kernel<<<ublocks, 256, 0, stream>>>(contents, Wu, bu, embEven);

    for (int l = 1; l < L_DIM; ++l) {
        float* cur        = (l & 1) ? out : embEven;
        const float* prev = (l & 1) ? embEven : out;
        u_kernel<<<ublocks, 256, 0, stream>>>(contents + (size_t)l * N_DIM * F_DIM,
                                              Wu, bu, cur);
        step_kernel<<<sblocks, 256, 0, stream>>>(prev, cur,
                                                 children + (size_t)(l - 1) * M_DIM * 2,
                                                 WrP, WhP, WzP, br, bh, bz);
    }
}

// Round 22
// 1219.283 us; speedup vs baseline: 4.7262x; 4.7262x over previous
//
#include <hip/hip_runtime.h>

#define L_DIM 16
#define N_DIM 200000
#define M_DIM 100000
#define F_DIM 7
#define H_DIM 64
#define NTILE (M_DIM / 32)   // 3125

typedef _Float16 f16;
typedef __attribute__((ext_vector_type(4))) _Float16 f16x4;
typedef __attribute__((ext_vector_type(8))) _Float16 f16x8;
typedef __attribute__((ext_vector_type(4))) float f32x4;

#define MFMA(a,b,c) __builtin_amdgcn_mfma_f32_16x16x32_f16((a),(b),(c),0,0,0)

// pack sizes (f16 elements)
#define NR_PK (192 * 192)
#define NH_PK (64 * 192)
#define NZ_PK (256 * 256)

__device__ __forceinline__ float tanh_(float x) {
    float e = __expf(2.f * x);
    return 1.f - 2.f / (e + 1.f);
}

// ---------------------------------------------------------------------------
// u = tanh(contents_l @ Wu.T + bu) -> out (N,64). 4 outputs/thread, float4 store.
// ---------------------------------------------------------------------------
__global__ __launch_bounds__(256) void u_kernel(const float* __restrict__ contents_l,
                                                const float* __restrict__ Wu,
                                                const float* __restrict__ bu,
                                                float* __restrict__ out) {
    __shared__ float sWu[H_DIM * F_DIM];
    __shared__ float sbu[H_DIM];
    int t = threadIdx.x;
    for (int idx = t; idx < H_DIM * F_DIM; idx += 256) sWu[idx] = Wu[idx];
    if (t < H_DIM) sbu[t] = bu[t];
    __syncthreads();

    int gid = blockIdx.x * 256 + t;
    int i = gid >> 4;
    int h0 = (gid & 15) * 4;
    if (i >= N_DIM) return;
    const float* c = contents_l + (size_t)i * F_DIM;
    float cv[F_DIM];
#pragma unroll
    for (int f = 0; f < F_DIM; ++f) cv[f] = c[f];
    float4 o;
#pragma unroll
    for (int q = 0; q < 4; ++q) {
        float acc = sbu[h0 + q];
#pragma unroll
        for (int f = 0; f < F_DIM; ++f) acc = fmaf(cv[f], sWu[(h0 + q) * F_DIM + f], acc);
        ((float*)&o)[q] = tanh_(acc);
    }
    *(float4*)(out + (size_t)i * H_DIM + h0) = o;
}

// ---------------------------------------------------------------------------
// Pack weights into MFMA fragment order with the custom2 k-rule (as R8):
//   koff(g4,j) = (j<4) ? 4*g4+j : 16+4*g4+(j-4)
//   value = W[16*t16 + (lane&15)][32*ks + koff(lane>>4, j)]
// ---------------------------------------------------------------------------
__global__ void prep_pack(const float* __restrict__ Wr, const float* __restrict__ Wh,
                          const float* __restrict__ Wz, f16* __restrict__ out) {
    int idx = blockIdx.x * 256 + threadIdx.x;
    if (idx >= NR_PK + NH_PK + NZ_PK) return;
    int e, Kdim, KS;
    const float* W;
    f16* dst;
    if (idx < NR_PK) { e = idx; W = Wr; Kdim = 192; KS = 6; dst = out; }
    else if (idx < NR_PK + NH_PK) { e = idx - NR_PK; W = Wh; Kdim = 192; KS = 6; dst = out + NR_PK; }
    else { e = idx - NR_PK - NH_PK; W = Wz; Kdim = 256; KS = 8; dst = out + NR_PK + NH_PK; }
    int j = e & 7;
    int l = (e >> 3) & 63;
    int tile = e >> 9;
    int ks = tile % KS;
    int t16 = tile / KS;
    int g4 = l >> 4;
    int koff = (j < 4) ? (4 * g4 + j) : (16 + 4 * g4 + (j - 4));
    int k = ks * 32 + koff;
    int n = t16 * 16 + (l & 15);
    dst[e] = (f16)W[n * Kdim + k];
}

// load an A/B fragment in custom2 layout from an fp32 row pointer (32-col slice)
__device__ __forceinline__ f16x8 frag2(const float* __restrict__ p, int g4) {
    float4 a = *(const float4*)(p + 4 * g4);
    float4 b = *(const float4*)(p + 16 + 4 * g4);
    f16x8 h = {(f16)a.x, (f16)a.y, (f16)a.z, (f16)a.w,
               (f16)b.x, (f16)b.y, (f16)b.z, (f16)b.w};
    return h;
}

// ---------------------------------------------------------------------------
// Fused step: 256 thr = 4 independent waves; wave does ONE tile
// blockIdx*4+wv, straight-line (multi-tile wrapping spills: R11/12/14/21).
// vs R20: LgL/LgR epilogue stashes REMOVED (epilogue re-gathers hL/hR from
// global, R10-style, ~2.5% cost per R13) -> LDS 77.8 -> 43 KB -> 3 blocks/CU
// = 12 resident waves/CU ~= the 12.2 waves of work -> single dispatch round.
// Keeps: __launch_bounds__(256,2) reg cap (R17) + Lr LDS hand-spill of
// aR[1] (R20).
// ---------------------------------------------------------------------------
__global__ __launch_bounds__(256, 2) void step_kernel(
    const float* __restrict__ embP,
    float* __restrict__ embC,
    const int* __restrict__ chl,
    const f16x8* __restrict__ WrP,
    const f16x8* __restrict__ WhP,
    const f16x8* __restrict__ WzP,
    const float* __restrict__ br,
    const float* __restrict__ bh,
    const float* __restrict__ bz)
{
    __shared__ f16 Lh[4][32][72];    // 18432 B: hH
    __shared__ f16x8 Lr[4][6][64];   // 24576 B: aR[rg=1] spill, lane-contiguous

    const int w = threadIdx.x >> 6;
    const int tile = blockIdx.x * 4 + w;
    if (tile >= NTILE) return;
    const int wbase = tile * 32;
    const int l = threadIdx.x & 63;
    const int l15 = l & 15;
    const int g4 = l >> 4;
    const f32x4 zz = {0.f, 0.f, 0.f, 0.f};

    // ---- gather: A-fragments of [hL|hR|u] straight to registers ----
    f16x8 aH[2][6];
#pragma unroll
    for (int rg = 0; rg < 2; ++rg) {
        int i = wbase + rg * 16 + l15;
        int iL = chl[2 * i], iR = chl[2 * i + 1];
        const float* pL = embP + (size_t)iL * 64;
        const float* pR = embP + (size_t)iR * 64;
        const float* pU = embC + (size_t)i * 64;
        aH[rg][0] = frag2(pL, g4);      aH[rg][1] = frag2(pL + 32, g4);
        aH[rg][2] = frag2(pR, g4);      aH[rg][3] = frag2(pR + 32, g4);
        aH[rg][4] = frag2(pU, g4);      aH[rg][5] = frag2(pU + 32, g4);
    }

    // ---- GEMM1 (transposed): aR = sigmoid(Wr @ hhu^T + br) * aH ----
    // aR[0][*] stays in regs; aR[1][*] streamed to LDS (Lr).
    f16x8 aR0[6];
#pragma unroll
    for (int kr = 0; kr < 6; ++kr) {
        f16x8 A[6];
#pragma unroll
        for (int ks = 0; ks < 6; ++ks) A[ks] = WrP[((2 * kr) * 6 + ks) * 64 + l];
        f32x4 c00 = zz, c01 = zz;
#pragma unroll
        for (int ks = 0; ks < 6; ++ks) {
            c00 = MFMA(A[ks], aH[0][ks], c00);
            c01 = MFMA(A[ks], aH[1][ks], c01);
        }
#pragma unroll
        for (int ks = 0; ks < 6; ++ks) A[ks] = WrP[((2 * kr + 1) * 6 + ks) * 64 + l];
        f32x4 c10 = zz, c11 = zz;
#pragma unroll
        for (int ks = 0; ks < 6; ++ks) {
            c10 = MFMA(A[ks], aH[0][ks], c10);
            c11 = MFMA(A[ks], aH[1][ks], c11);
        }
        float4 bA = *(const float4*)(br + 32 * kr + 4 * g4);
        float4 bB = *(const float4*)(br + 32 * kr + 16 + 4 * g4);
#pragma unroll
        for (int rg = 0; rg < 2; ++rg) {
            f32x4 clo = (rg == 0) ? c00 : c01;
            f32x4 chi = (rg == 0) ? c10 : c11;
            f16x8 h = aH[rg][kr];
            float s0 = 1.f / (1.f + __expf(-(clo[0] + bA.x)));
            float s1 = 1.f / (1.f + __expf(-(clo[1] + bA.y)));
            float s2 = 1.f / (1.f + __expf(-(clo[2] + bA.z)));
            float s3 = 1.f / (1.f + __expf(-(clo[3] + bA.w)));
            float s4 = 1.f / (1.f + __expf(-(chi[0] + bB.x)));
            float s5 = 1.f / (1.f + __expf(-(chi[1] + bB.y)));
            float s6 = 1.f / (1.f + __expf(-(chi[2] + bB.z)));
            float s7 = 1.f / (1.f + __expf(-(chi[3] + bB.w)));
            f16x8 o = {(f16)(s0 * (float)h[0]), (f16)(s1 * (float)h[1]),
                       (f16)(s2 * (float)h[2]), (f16)(s3 * (float)h[3]),
                       (f16)(s4 * (float)h[4]), (f16)(s5 * (float)h[5]),
                       (f16)(s6 * (float)h[6]), (f16)(s7 * (float)h[7])};
            if (rg == 0) aR0[kr] = o;
            else         Lr[w][kr][l] = o;      // LDS spill (wave-local)
        }
    }

    // ---- GEMM2 (transposed ONLY): ht[rg][t4] = Wh_t4 @ rh^T ----
    f32x4 ht[2][4];
#pragma unroll
    for (int rg = 0; rg < 2; ++rg)
#pragma unroll
        for (int t4 = 0; t4 < 4; ++t4) ht[rg][t4] = zz;
#pragma unroll
    for (int ks = 0; ks < 6; ++ks) {
        f16x8 Wt[4];
#pragma unroll
        for (int t4 = 0; t4 < 4; ++t4) Wt[t4] = WhP[(t4 * 6 + ks) * 64 + l];
        f16x8 a1 = Lr[w][ks][l];                // LDS reload (wave-local)
#pragma unroll
        for (int t4 = 0; t4 < 4; ++t4) {
            ht[0][t4] = MFMA(Wt[t4], aR0[ks], ht[0][t4]);
            ht[1][t4] = MFMA(Wt[t4], a1, ht[1][t4]);
        }
    }

    // ---- tanh; build aZ in regs; stash hH to Lh for the epilogue ----
    // ht[rg][t4][r] at lane l = hH[row = rg*16+l15][h_col = 16*t4 + 4*g4 + r]
    f16x8 aZ[2][2];
    {
        float4 bh0 = *(const float4*)(bh + 4 * g4);
        float4 bh1 = *(const float4*)(bh + 16 + 4 * g4);
        float4 bh2 = *(const float4*)(bh + 32 + 4 * g4);
        float4 bh3 = *(const float4*)(bh + 48 + 4 * g4);
#pragma unroll
        for (int rg = 0; rg < 2; ++rg) {
            f16x4 th0 = {(f16)tanh_(ht[rg][0][0] + bh0.x), (f16)tanh_(ht[rg][0][1] + bh0.y),
                         (f16)tanh_(ht[rg][0][2] + bh0.z), (f16)tanh_(ht[rg][0][3] + bh0.w)};
            f16x4 th1 = {(f16)tanh_(ht[rg][1][0] + bh1.x), (f16)tanh_(ht[rg][1][1] + bh1.y),
                         (f16)tanh_(ht[rg][1][2] + bh1.z), (f16)tanh_(ht[rg][1][3] + bh1.w)};
            f16x4 th2 = {(f16)tanh_(ht[rg][2][0] + bh2.x), (f16)tanh_(ht[rg][2][1] + bh2.y),
                         (f16)tanh_(ht[rg][2][2] + bh2.z), (f16)tanh_(ht[rg][2][3] + bh2.w)};
            f16x4 th3 = {(f16)tanh_(ht[rg][3][0] + bh3.x), (f16)tanh_(ht[rg][3][1] + bh3.y),
                         (f16)tanh_(ht[rg][3][2] + bh3.z), (f16)tanh_(ht[rg][3][3] + bh3.w)};
            int row = rg * 16 + l15;
            *(f16x4*)&Lh[w][row][4 * g4]      = th0;
            *(f16x4*)&Lh[w][row][16 + 4 * g4] = th1;
            *(f16x4*)&Lh[w][row][32 + 4 * g4] = th2;
            *(f16x4*)&Lh[w][row][48 + 4 * g4] = th3;
            aZ[rg][0] = (f16x8){th0[0], th0[1], th0[2], th0[3],
                                th1[0], th1[1], th1[2], th1[3]};
            aZ[rg][1] = (f16x8){th2[0], th2[1], th2[2], th2[3],
                                th3[0], th3[1], th3[2], th3[3]};
        }
    }

    // ---- children for epilogue rows (R10-style re-gather) ----
    int iLr[2][4], iRr[2][4];
#pragma unroll
    for (int rg = 0; rg < 2; ++rg)
#pragma unroll
        for (int r = 0; r < 4; ++r) {
            int i = wbase + rg * 16 + 4 * g4 + r;
            iLr[rg][r] = chl[2 * i];
            iRr[rg][r] = chl[2 * i + 1];
        }

    // ---- GEMM3 (normal) + fused epilogue per 16-col group T ----
#pragma unroll
    for (int T = 0; T < 4; ++T) {
        f32x4 ac[2][4];
#pragma unroll
        for (int g = 0; g < 4; ++g) {
            int nt = g * 4 + T;
            f16x8 bb[8];
#pragma unroll
            for (int ks = 0; ks < 8; ++ks) bb[ks] = WzP[(nt * 8 + ks) * 64 + l];
#pragma unroll
            for (int rg = 0; rg < 2; ++rg) {
                f32x4 a = zz;
                a = MFMA(aZ[rg][0], bb[0], a);
                a = MFMA(aZ[rg][1], bb[1], a);
#pragma unroll
                for (int ks = 2; ks < 8; ++ks) a = MFMA(aH[rg][ks - 2], bb[ks], a);
                ac[rg][g] = a;
            }
        }
        int col = T * 16 + l15;
        float b0 = bz[col], b1 = bz[64 + col], b2 = bz[128 + col], b3 = bz[192 + col];
#pragma unroll
        for (int rg = 0; rg < 2; ++rg)
#pragma unroll
            for (int r = 0; r < 4; ++r) {
                int row = rg * 16 + 4 * g4 + r;
                int i = wbase + row;
                float z0 = ac[rg][0][r] + b0;
                float z1 = ac[rg][1][r] + b1;
                float z2 = ac[rg][2][r] + b2;
                float z3 = ac[rg][3][r] + b3;
                float mx = fmaxf(fmaxf(z0, z1), fmaxf(z2, z3));
                float e0 = __expf(z0 - mx), e1 = __expf(z1 - mx);
                float e2 = __expf(z2 - mx), e3 = __expf(z3 - mx);
                float rs = __frcp_rn(e0 + e1 + e2 + e3);
                float hHv = (float)Lh[w][row][col];
                float hLv = embP[(size_t)iLr[rg][r] * 64 + col];
                float hRv = embP[(size_t)iRr[rg][r] * 64 + col];
                float uv  = embC[(size_t)i * 64 + col];     // read-before-write
                embC[(size_t)i * 64 + col] =
                    (e0 * hHv + e1 * hLv + e2 * hRv + e3 * uv) * rs;
            }
    }
}

// ---------------------------------------------------------------------------
extern "C" void kernel_launch(void* const* d_in, const int* in_sizes, int n_in,
                              void* d_out, int out_size, void* d_ws, size_t ws_size,
                              hipStream_t stream) {
    const float* contents = (const float*)d_in[0];
    const int*   children = (const int*)d_in[1];
    const float* Wu = (const float*)d_in[2];
    const float* bu = (const float*)d_in[3];
    const float* Wh = (const float*)d_in[4];
    const float* bh = (const float*)d_in[5];
    const float* Wz = (const float*)d_in[6];
    const float* bz = (const float*)d_in[7];
    const float* Wr = (const float*)d_in[8];
    const float* br = (const float*)d_in[9];
    float* out = (float*)d_out;
    float* ws  = (float*)d_ws;

    float* embEven = ws;                             // N*64 fp32
    f16*   pack    = (f16*)(ws + (size_t)N_DIM * H_DIM);
    const f16x8* WrP = (const f16x8*)pack;
    const f16x8* WhP = (const f16x8*)(pack + NR_PK);
    const f16x8* WzP = (const f16x8*)(pack + NR_PK + NH_PK);

    const int NPK = NR_PK + NH_PK + NZ_PK;
    prep_pack<<<(NPK + 255) / 256, 256, 0, stream>>>(Wr, Wh, Wz, pack);

    int ublocks = (N_DIM * 16 + 255) / 256;   // 12500
    int sblocks = (NTILE + 3) / 4;            // 782 wgs x 4 waves

    u_kernel<<<ublocks, 256, 0, stream>>>(contents, Wu, bu, embEven);

    for (int l = 1; l < L_DIM; ++l) {
        float* cur        = (l & 1) ? out : embEven;
        const float* prev = (l & 1) ? embEven : out;
        u_kernel<<<ublocks, 256, 0, stream>>>(contents + (size_t)l * N_DIM * F_DIM,
                                              Wu, bu, cur);
        step_kernel<<<sblocks, 256, 0, stream>>>(prev, cur,
                                                 children + (size_t)(l - 1) * M_DIM * 2,
                                                 WrP, WhP, WzP, br, bh, bz);
    }
}

// Round 23
// 1174.516 us; speedup vs baseline: 4.9064x; 1.0381x over previous
//
#include <hip/hip_runtime.h>

#define L_DIM 16
#define N_DIM 200000
#define M_DIM 100000
#define F_DIM 7
#define H_DIM 64
#define NTILE (M_DIM / 32)   // 3125

typedef _Float16 f16;
typedef __attribute__((ext_vector_type(4))) _Float16 f16x4;
typedef __attribute__((ext_vector_type(8))) _Float16 f16x8;
typedef __attribute__((ext_vector_type(4))) float f32x4;

#define MFMA(a,b,c) __builtin_amdgcn_mfma_f32_16x16x32_f16((a),(b),(c),0,0,0)

// pack sizes (f16 elements)
#define NR_PK (192 * 192)
#define NH_PK (64 * 192)
#define NZ_PK (256 * 256)

__device__ __forceinline__ float tanh_(float x) {
    float e = __expf(2.f * x);
    return 1.f - 2.f / (e + 1.f);
}

// ---------------------------------------------------------------------------
// u = tanh(contents_l @ Wu.T + bu) -> out (N,64). 4 outputs/thread, float4 store.
// ---------------------------------------------------------------------------
__global__ __launch_bounds__(256) void u_kernel(const float* __restrict__ contents_l,
                                                const float* __restrict__ Wu,
                                                const float* __restrict__ bu,
                                                float* __restrict__ out) {
    __shared__ float sWu[H_DIM * F_DIM];
    __shared__ float sbu[H_DIM];
    int t = threadIdx.x;
    for (int idx = t; idx < H_DIM * F_DIM; idx += 256) sWu[idx] = Wu[idx];
    if (t < H_DIM) sbu[t] = bu[t];
    __syncthreads();

    int gid = blockIdx.x * 256 + t;
    int i = gid >> 4;
    int h0 = (gid & 15) * 4;
    if (i >= N_DIM) return;
    const float* c = contents_l + (size_t)i * F_DIM;
    float cv[F_DIM];
#pragma unroll
    for (int f = 0; f < F_DIM; ++f) cv[f] = c[f];
    float4 o;
#pragma unroll
    for (int q = 0; q < 4; ++q) {
        float acc = sbu[h0 + q];
#pragma unroll
        for (int f = 0; f < F_DIM; ++f) acc = fmaf(cv[f], sWu[(h0 + q) * F_DIM + f], acc);
        ((float*)&o)[q] = tanh_(acc);
    }
    *(float4*)(out + (size_t)i * H_DIM + h0) = o;
}

// ---------------------------------------------------------------------------
// Pack weights into MFMA fragment order with the custom2 k-rule (as R8):
//   koff(g4,j) = (j<4) ? 4*g4+j : 16+4*g4+(j-4)
//   value = W[16*t16 + (lane&15)][32*ks + koff(lane>>4, j)]
// ---------------------------------------------------------------------------
__global__ void prep_pack(const float* __restrict__ Wr, const float* __restrict__ Wh,
                          const float* __restrict__ Wz, f16* __restrict__ out) {
    int idx = blockIdx.x * 256 + threadIdx.x;
    if (idx >= NR_PK + NH_PK + NZ_PK) return;
    int e, Kdim, KS;
    const float* W;
    f16* dst;
    if (idx < NR_PK) { e = idx; W = Wr; Kdim = 192; KS = 6; dst = out; }
    else if (idx < NR_PK + NH_PK) { e = idx - NR_PK; W = Wh; Kdim = 192; KS = 6; dst = out + NR_PK; }
    else { e = idx - NR_PK - NH_PK; W = Wz; Kdim = 256; KS = 8; dst = out + NR_PK + NH_PK; }
    int j = e & 7;
    int l = (e >> 3) & 63;
    int tile = e >> 9;
    int ks = tile % KS;
    int t16 = tile / KS;
    int g4 = l >> 4;
    int koff = (j < 4) ? (4 * g4 + j) : (16 + 4 * g4 + (j - 4));
    int k = ks * 32 + koff;
    int n = t16 * 16 + (l & 15);
    dst[e] = (f16)W[n * Kdim + k];
}

// load an A/B fragment in custom2 layout from an fp32 row pointer (32-col slice)
__device__ __forceinline__ f16x8 frag2(const float* __restrict__ p, int g4) {
    float4 a = *(const float4*)(p + 4 * g4);
    float4 b = *(const float4*)(p + 16 + 4 * g4);
    f16x8 h = {(f16)a.x, (f16)a.y, (f16)a.z, (f16)a.w,
               (f16)b.x, (f16)b.y, (f16)b.z, (f16)b.w};
    return h;
}

// ---------------------------------------------------------------------------
// Fused step: R20 champion body (one tile per wave, straight-line,
// __launch_bounds__(256,2), aR[1] hand-spilled to LDS Lr, hL/hR/hH stashed
// in LDS for the epilogue) + s_setprio(1) around the MFMA chain regions.
// Waves here are INDEPENDENT (no barriers) at different phases -- the
// pattern where setprio measured +4-7% (attn, m191); it was only null for
// barrier-lockstep GEMM (m190).
// ---------------------------------------------------------------------------
__global__ __launch_bounds__(256, 2) void step_kernel(
    const float* __restrict__ embP,
    float* __restrict__ embC,
    const int* __restrict__ chl,
    const f16x8* __restrict__ WrP,
    const f16x8* __restrict__ WhP,
    const f16x8* __restrict__ WzP,
    const float* __restrict__ br,
    const float* __restrict__ bh,
    const float* __restrict__ bz)
{
    __shared__ f16 LgL[4][32][68];   // 17408 B: hL (natural col order)
    __shared__ f16 LgR[4][32][68];   // 17408 B: hR
    __shared__ f16 Lh[4][32][72];    // 18432 B: hH
    __shared__ f16x8 Lr[4][6][64];   // 24576 B: aR[rg=1] spill, lane-contiguous

    const int w = threadIdx.x >> 6;
    const int tile = blockIdx.x * 4 + w;
    if (tile >= NTILE) return;
    const int wbase = tile * 32;
    const int l = threadIdx.x & 63;
    const int l15 = l & 15;
    const int g4 = l >> 4;
    const f32x4 zz = {0.f, 0.f, 0.f, 0.f};

    // ---- gather: A-fragments of [hL|hR|u]; stash hL/hR to LDS ----
    f16x8 aH[2][6];
#pragma unroll
    for (int rg = 0; rg < 2; ++rg) {
        int i = wbase + rg * 16 + l15;
        int iL = chl[2 * i], iR = chl[2 * i + 1];
        const float* pL = embP + (size_t)iL * 64;
        const float* pR = embP + (size_t)iR * 64;
        const float* pU = embC + (size_t)i * 64;
        aH[rg][0] = frag2(pL, g4);      aH[rg][1] = frag2(pL + 32, g4);
        aH[rg][2] = frag2(pR, g4);      aH[rg][3] = frag2(pR + 32, g4);
        aH[rg][4] = frag2(pU, g4);      aH[rg][5] = frag2(pU + 32, g4);

        int row = rg * 16 + l15;
        // custom2 inverse: elems 0..3 -> cols base+4g4, elems 4..7 -> base+16+4g4
        f16x8 hA = aH[rg][0], hB = aH[rg][1];
        *(f16x4*)&LgL[w][row][4 * g4]      = (f16x4){hA[0], hA[1], hA[2], hA[3]};
        *(f16x4*)&LgL[w][row][16 + 4 * g4] = (f16x4){hA[4], hA[5], hA[6], hA[7]};
        *(f16x4*)&LgL[w][row][32 + 4 * g4] = (f16x4){hB[0], hB[1], hB[2], hB[3]};
        *(f16x4*)&LgL[w][row][48 + 4 * g4] = (f16x4){hB[4], hB[5], hB[6], hB[7]};
        f16x8 rA = aH[rg][2], rB = aH[rg][3];
        *(f16x4*)&LgR[w][row][4 * g4]      = (f16x4){rA[0], rA[1], rA[2], rA[3]};
        *(f16x4*)&LgR[w][row][16 + 4 * g4] = (f16x4){rA[4], rA[5], rA[6], rA[7]};
        *(f16x4*)&LgR[w][row][32 + 4 * g4] = (f16x4){rB[0], rB[1], rB[2], rB[3]};
        *(f16x4*)&LgR[w][row][48 + 4 * g4] = (f16x4){rB[4], rB[5], rB[6], rB[7]};
    }

    // ---- GEMM1 (transposed): aR = sigmoid(Wr @ hhu^T + br) * aH ----
    // aR[0][*] stays in regs; aR[1][*] streamed to LDS (Lr).
    f16x8 aR0[6];
#pragma unroll
    for (int kr = 0; kr < 6; ++kr) {
        f16x8 A[6];
#pragma unroll
        for (int ks = 0; ks < 6; ++ks) A[ks] = WrP[((2 * kr) * 6 + ks) * 64 + l];
        f32x4 c00 = zz, c01 = zz;
        __builtin_amdgcn_s_setprio(1);
#pragma unroll
        for (int ks = 0; ks < 6; ++ks) {
            c00 = MFMA(A[ks], aH[0][ks], c00);
            c01 = MFMA(A[ks], aH[1][ks], c01);
        }
        __builtin_amdgcn_s_setprio(0);
#pragma unroll
        for (int ks = 0; ks < 6; ++ks) A[ks] = WrP[((2 * kr + 1) * 6 + ks) * 64 + l];
        f32x4 c10 = zz, c11 = zz;
        __builtin_amdgcn_s_setprio(1);
#pragma unroll
        for (int ks = 0; ks < 6; ++ks) {
            c10 = MFMA(A[ks], aH[0][ks], c10);
            c11 = MFMA(A[ks], aH[1][ks], c11);
        }
        __builtin_amdgcn_s_setprio(0);
        float4 bA = *(const float4*)(br + 32 * kr + 4 * g4);
        float4 bB = *(const float4*)(br + 32 * kr + 16 + 4 * g4);
#pragma unroll
        for (int rg = 0; rg < 2; ++rg) {
            f32x4 clo = (rg == 0) ? c00 : c01;
            f32x4 chi = (rg == 0) ? c10 : c11;
            f16x8 h = aH[rg][kr];
            float s0 = 1.f / (1.f + __expf(-(clo[0] + bA.x)));
            float s1 = 1.f / (1.f + __expf(-(clo[1] + bA.y)));
            float s2 = 1.f / (1.f + __expf(-(clo[2] + bA.z)));
            float s3 = 1.f / (1.f + __expf(-(clo[3] + bA.w)));
            float s4 = 1.f / (1.f + __expf(-(chi[0] + bB.x)));
            float s5 = 1.f / (1.f + __expf(-(chi[1] + bB.y)));
            float s6 = 1.f / (1.f + __expf(-(chi[2] + bB.z)));
            float s7 = 1.f / (1.f + __expf(-(chi[3] + bB.w)));
            f16x8 o = {(f16)(s0 * (float)h[0]), (f16)(s1 * (float)h[1]),
                       (f16)(s2 * (float)h[2]), (f16)(s3 * (float)h[3]),
                       (f16)(s4 * (float)h[4]), (f16)(s5 * (float)h[5]),
                       (f16)(s6 * (float)h[6]), (f16)(s7 * (float)h[7])};
            if (rg == 0) aR0[kr] = o;
            else         Lr[w][kr][l] = o;      // LDS spill (wave-local)
        }
    }

    // ---- GEMM2 (transposed ONLY): ht[rg][t4] = Wh_t4 @ rh^T ----
    f32x4 ht[2][4];
#pragma unroll
    for (int rg = 0; rg < 2; ++rg)
#pragma unroll
        for (int t4 = 0; t4 < 4; ++t4) ht[rg][t4] = zz;
#pragma unroll
    for (int ks = 0; ks < 6; ++ks) {
        f16x8 Wt[4];
#pragma unroll
        for (int t4 = 0; t4 < 4; ++t4) Wt[t4] = WhP[(t4 * 6 + ks) * 64 + l];
        f16x8 a1 = Lr[w][ks][l];                // LDS reload (wave-local)
        __builtin_amdgcn_s_setprio(1);
#pragma unroll
        for (int t4 = 0; t4 < 4; ++t4) {
            ht[0][t4] = MFMA(Wt[t4], aR0[ks], ht[0][t4]);
            ht[1][t4] = MFMA(Wt[t4], a1, ht[1][t4]);
        }
        __builtin_amdgcn_s_setprio(0);
    }

    // ---- tanh; build aZ in regs; stash hH to Lh for the epilogue ----
    f16x8 aZ[2][2];
    {
        float4 bh0 = *(const float4*)(bh + 4 * g4);
        float4 bh1 = *(const float4*)(bh + 16 + 4 * g4);
        float4 bh2 = *(const float4*)(bh + 32 + 4 * g4);
        float4 bh3 = *(const float4*)(bh + 48 + 4 * g4);
#pragma unroll
        for (int rg = 0; rg < 2; ++rg) {
            f16x4 th0 = {(f16)tanh_(ht[rg][0][0] + bh0.x), (f16)tanh_(ht[rg][0][1] + bh0.y),
                         (f16)tanh_(ht[rg][0][2] + bh0.z), (f16)tanh_(ht[rg][0][3] + bh0.w)};
            f16x4 th1 = {(f16)tanh_(ht[rg][1][0] + bh1.x), (f16)tanh_(ht[rg][1][1] + bh1.y),
                         (f16)tanh_(ht[rg][1][2] + bh1.z), (f16)tanh_(ht[rg][1][3] + bh1.w)};
            f16x4 th2 = {(f16)tanh_(ht[rg][2][0] + bh2.x), (f16)tanh_(ht[rg][2][1] + bh2.y),
                         (f16)tanh_(ht[rg][2][2] + bh2.z), (f16)tanh_(ht[rg][2][3] + bh2.w)};
            f16x4 th3 = {(f16)tanh_(ht[rg][3][0] + bh3.x), (f16)tanh_(ht[rg][3][1] + bh3.y),
                         (f16)tanh_(ht[rg][3][2] + bh3.z), (f16)tanh_(ht[rg][3][3] + bh3.w)};
            int row = rg * 16 + l15;
            *(f16x4*)&Lh[w][row][4 * g4]      = th0;
            *(f16x4*)&Lh[w][row][16 + 4 * g4] = th1;
            *(f16x4*)&Lh[w][row][32 + 4 * g4] = th2;
            *(f16x4*)&Lh[w][row][48 + 4 * g4] = th3;
            aZ[rg][0] = (f16x8){th0[0], th0[1], th0[2], th0[3],
                                th1[0], th1[1], th1[2], th1[3]};
            aZ[rg][1] = (f16x8){th2[0], th2[1], th2[2], th2[3],
                                th3[0], th3[1], th3[2], th3[3]};
        }
    }

    // ---- GEMM3 (normal) + fused epilogue per 16-col group T ----
#pragma unroll
    for (int T = 0; T < 4; ++T) {
        f32x4 ac[2][4];
#pragma unroll
        for (int g = 0; g < 4; ++g) {
            int nt = g * 4 + T;
            f16x8 bb[8];
#pragma unroll
            for (int ks = 0; ks < 8; ++ks) bb[ks] = WzP[(nt * 8 + ks) * 64 + l];
            __builtin_amdgcn_s_setprio(1);
#pragma unroll
            for (int rg = 0; rg < 2; ++rg) {
                f32x4 a = zz;
                a = MFMA(aZ[rg][0], bb[0], a);
                a = MFMA(aZ[rg][1], bb[1], a);
#pragma unroll
                for (int ks = 2; ks < 8; ++ks) a = MFMA(aH[rg][ks - 2], bb[ks], a);
                ac[rg][g] = a;
            }
            __builtin_amdgcn_s_setprio(0);
        }
        int col = T * 16 + l15;
        float b0 = bz[col], b1 = bz[64 + col], b2 = bz[128 + col], b3 = bz[192 + col];
#pragma unroll
        for (int rg = 0; rg < 2; ++rg)
#pragma unroll
            for (int r = 0; r < 4; ++r) {
                int row = rg * 16 + 4 * g4 + r;
                int i = wbase + row;
                float z0 = ac[rg][0][r] + b0;
                float z1 = ac[rg][1][r] + b1;
                float z2 = ac[rg][2][r] + b2;
                float z3 = ac[rg][3][r] + b3;
                float mx = fmaxf(fmaxf(z0, z1), fmaxf(z2, z3));
                float e0 = __expf(z0 - mx), e1 = __expf(z1 - mx);
                float e2 = __expf(z2 - mx), e3 = __expf(z3 - mx);
                float rs = __frcp_rn(e0 + e1 + e2 + e3);
                float hHv = (float)Lh[w][row][col];
                float hLv = (float)LgL[w][row][col];
                float hRv = (float)LgR[w][row][col];
                float uv  = embC[(size_t)i * 64 + col];     // read-before-write
                embC[(size_t)i * 64 + col] =
                    (e0 * hHv + e1 * hLv + e2 * hRv + e3 * uv) * rs;
            }
    }
}

// ---------------------------------------------------------------------------
extern "C" void kernel_launch(void* const* d_in, const int* in_sizes, int n_in,
                              void* d_out, int out_size, void* d_ws, size_t ws_size,
                              hipStream_t stream) {
    const float* contents = (const float*)d_in[0];
    const int*   children = (const int*)d_in[1];
    const float* Wu = (const float*)d_in[2];
    const float* bu = (const float*)d_in[3];
    const float* Wh = (const float*)d_in[4];
    const float* bh = (const float*)d_in[5];
    const float* Wz = (const float*)d_in[6];
    const float* bz = (const float*)d_in[7];
    const float* Wr = (const float*)d_in[8];
    const float* br = (const float*)d_in[9];
    float* out = (float*)d_out;
    float* ws  = (float*)d_ws;

    float* embEven = ws;                             // N*64 fp32
    f16*   pack    = (f16*)(ws + (size_t)N_DIM * H_DIM);
    const f16x8* WrP = (const f16x8*)pack;
    const f16x8* WhP = (const f16x8*)(pack + NR_PK);
    const f16x8* WzP = (const f16x8*)(pack + NR_PK + NH_PK);

    const int NPK = NR_PK + NH_PK + NZ_PK;
    prep_pack<<<(NPK + 255) / 256, 256, 0, stream>>>(Wr, Wh, Wz, pack);

    int ublocks = (N_DIM * 16 + 255) / 256;   // 12500
    int sblocks = (NTILE + 3) / 4;            // 782 wgs x 4 waves

    u_kernel<<<ublocks, 256, 0, stream>>>(contents, Wu, bu, embEven);

    for (int l = 1; l < L_DIM; ++l) {
        float* cur        = (l & 1) ? out : embEven;
        const float* prev = (l & 1) ? embEven : out;
        u_kernel<<<ublocks, 256, 0, stream>>>(contents + (size_t)l * N_DIM * F_DIM,
                                              Wu, bu, cur);
        step_kernel<<<sblocks, 256, 0, stream>>>(prev, cur,
                                                 children + (size_t)(l - 1) * M_DIM * 2,
                                                 WrP, WhP, WzP, br, bh, bz);
    }
}

// Round 24
// 1089.254 us; speedup vs baseline: 5.2904x; 1.0783x over previous
//
#include <hip/hip_runtime.h>

#define L_DIM 16
#define N_DIM 200000
#define M_DIM 100000
#define F_DIM 7
#define H_DIM 64
#define NTILE (M_DIM / 32)   // 3125

typedef _Float16 f16;
typedef __attribute__((ext_vector_type(4))) _Float16 f16x4;
typedef __attribute__((ext_vector_type(8))) _Float16 f16x8;
typedef __attribute__((ext_vector_type(4))) float f32x4;

#define MFMA(a,b,c) __builtin_amdgcn_mfma_f32_16x16x32_f16((a),(b),(c),0,0,0)

// pack sizes (f16 elements)
#define NR_PK (192 * 192)
#define NH_PK (64 * 192)
#define NZ_PK (256 * 256)

__device__ __forceinline__ float tanh_(float x) {
    float e = __expf(2.f * x);
    return 1.f - 2.f / (e + 1.f);
}

// ---------------------------------------------------------------------------
// u = tanh(contents_l @ Wu.T + bu) -> out (N,64). 4 outputs/thread, float4 store.
// ---------------------------------------------------------------------------
__global__ __launch_bounds__(256) void u_kernel(const float* __restrict__ contents_l,
                                                const float* __restrict__ Wu,
                                                const float* __restrict__ bu,
                                                float* __restrict__ out) {
    __shared__ float sWu[H_DIM * F_DIM];
    __shared__ float sbu[H_DIM];
    int t = threadIdx.x;
    for (int idx = t; idx < H_DIM * F_DIM; idx += 256) sWu[idx] = Wu[idx];
    if (t < H_DIM) sbu[t] = bu[t];
    __syncthreads();

    int gid = blockIdx.x * 256 + t;
    int i = gid >> 4;
    int h0 = (gid & 15) * 4;
    if (i >= N_DIM) return;
    const float* c = contents_l + (size_t)i * F_DIM;
    float cv[F_DIM];
#pragma unroll
    for (int f = 0; f < F_DIM; ++f) cv[f] = c[f];
    float4 o;
#pragma unroll
    for (int q = 0; q < 4; ++q) {
        float acc = sbu[h0 + q];
#pragma unroll
        for (int f = 0; f < F_DIM; ++f) acc = fmaf(cv[f], sWu[(h0 + q) * F_DIM + f], acc);
        ((float*)&o)[q] = tanh_(acc);
    }
    *(float4*)(out + (size_t)i * H_DIM + h0) = o;
}

// ---------------------------------------------------------------------------
// Pack weights into MFMA fragment order with the custom2 k-rule (as R8):
//   koff(g4,j) = (j<4) ? 4*g4+j : 16+4*g4+(j-4)
//   value = W[16*t16 + (lane&15)][32*ks + koff(lane>>4, j)]
// ---------------------------------------------------------------------------
__global__ void prep_pack(const float* __restrict__ Wr, const float* __restrict__ Wh,
                          const float* __restrict__ Wz, f16* __restrict__ out) {
    int idx = blockIdx.x * 256 + threadIdx.x;
    if (idx >= NR_PK + NH_PK + NZ_PK) return;
    int e, Kdim, KS;
    const float* W;
    f16* dst;
    if (idx < NR_PK) { e = idx; W = Wr; Kdim = 192; KS = 6; dst = out; }
    else if (idx < NR_PK + NH_PK) { e = idx - NR_PK; W = Wh; Kdim = 192; KS = 6; dst = out + NR_PK; }
    else { e = idx - NR_PK - NH_PK; W = Wz; Kdim = 256; KS = 8; dst = out + NR_PK + NH_PK; }
    int j = e & 7;
    int l = (e >> 3) & 63;
    int tile = e >> 9;
    int ks = tile % KS;
    int t16 = tile / KS;
    int g4 = l >> 4;
    int koff = (j < 4) ? (4 * g4 + j) : (16 + 4 * g4 + (j - 4));
    int k = ks * 32 + koff;
    int n = t16 * 16 + (l & 15);
    dst[e] = (f16)W[n * Kdim + k];
}

// load an A/B fragment in custom2 layout from an fp32 row pointer (32-col slice)
__device__ __forceinline__ f16x8 frag2(const float* __restrict__ p, int g4) {
    float4 a = *(const float4*)(p + 4 * g4);
    float4 b = *(const float4*)(p + 16 + 4 * g4);
    f16x8 h = {(f16)a.x, (f16)a.y, (f16)a.z, (f16)a.w,
               (f16)b.x, (f16)b.y, (f16)b.z, (f16)b.w};
    return h;
}

// ---------------------------------------------------------------------------
// Fused step (CHAMPION, R20): 256 thr = 4 independent waves; wave does ONE
// tile blockIdx*4+wv, straight-line, unfused GEMM1/GEMM2, with
// __launch_bounds__(256,2) (2 waves/SIMD via unified VGPR+AGPR cap, R17)
// and aR[1] hand-spilled to LDS (Lr) replacing allocator HBM-scratch (R20).
// Falsified alternatives: multi-tile loops/calls/inlining (R11/12/14/21:
// regalloc breaks -> 90-480MB scratch), 3 waves/SIMD (R18: spill cliff),
// GEMM1+2 fusion under cap (R19), LDS diet for 3 blocks/CU (R22), setprio
// (R23). This body is a regalloc-constrained fixed point.
// ---------------------------------------------------------------------------
__global__ __launch_bounds__(256, 2) void step_kernel(
    const float* __restrict__ embP,
    float* __restrict__ embC,
    const int* __restrict__ chl,
    const f16x8* __restrict__ WrP,
    const f16x8* __restrict__ WhP,
    const f16x8* __restrict__ WzP,
    const float* __restrict__ br,
    const float* __restrict__ bh,
    const float* __restrict__ bz)
{
    __shared__ f16 LgL[4][32][68];   // 17408 B: hL (natural col order)
    __shared__ f16 LgR[4][32][68];   // 17408 B: hR
    __shared__ f16 Lh[4][32][72];    // 18432 B: hH
    __shared__ f16x8 Lr[4][6][64];   // 24576 B: aR[rg=1] spill, lane-contiguous

    const int w = threadIdx.x >> 6;
    const int tile = blockIdx.x * 4 + w;
    if (tile >= NTILE) return;
    const int wbase = tile * 32;
    const int l = threadIdx.x & 63;
    const int l15 = l & 15;
    const int g4 = l >> 4;
    const f32x4 zz = {0.f, 0.f, 0.f, 0.f};

    // ---- gather: A-fragments of [hL|hR|u]; stash hL/hR to LDS ----
    f16x8 aH[2][6];
#pragma unroll
    for (int rg = 0; rg < 2; ++rg) {
        int i = wbase + rg * 16 + l15;
        int iL = chl[2 * i], iR = chl[2 * i + 1];
        const float* pL = embP + (size_t)iL * 64;
        const float* pR = embP + (size_t)iR * 64;
        const float* pU = embC + (size_t)i * 64;
        aH[rg][0] = frag2(pL, g4);      aH[rg][1] = frag2(pL + 32, g4);
        aH[rg][2] = frag2(pR, g4);      aH[rg][3] = frag2(pR + 32, g4);
        aH[rg][4] = frag2(pU, g4);      aH[rg][5] = frag2(pU + 32, g4);

        int row = rg * 16 + l15;
        // custom2 inverse: elems 0..3 -> cols base+4g4, elems 4..7 -> base+16+4g4
        f16x8 hA = aH[rg][0], hB = aH[rg][1];
        *(f16x4*)&LgL[w][row][4 * g4]      = (f16x4){hA[0], hA[1], hA[2], hA[3]};
        *(f16x4*)&LgL[w][row][16 + 4 * g4] = (f16x4){hA[4], hA[5], hA[6], hA[7]};
        *(f16x4*)&LgL[w][row][32 + 4 * g4] = (f16x4){hB[0], hB[1], hB[2], hB[3]};
        *(f16x4*)&LgL[w][row][48 + 4 * g4] = (f16x4){hB[4], hB[5], hB[6], hB[7]};
        f16x8 rA = aH[rg][2], rB = aH[rg][3];
        *(f16x4*)&LgR[w][row][4 * g4]      = (f16x4){rA[0], rA[1], rA[2], rA[3]};
        *(f16x4*)&LgR[w][row][16 + 4 * g4] = (f16x4){rA[4], rA[5], rA[6], rA[7]};
        *(f16x4*)&LgR[w][row][32 + 4 * g4] = (f16x4){rB[0], rB[1], rB[2], rB[3]};
        *(f16x4*)&LgR[w][row][48 + 4 * g4] = (f16x4){rB[4], rB[5], rB[6], rB[7]};
    }

    // ---- GEMM1 (transposed): aR = sigmoid(Wr @ hhu^T + br) * aH ----
    // aR[0][*] stays in regs; aR[1][*] streamed to LDS (Lr).
    f16x8 aR0[6];
#pragma unroll
    for (int kr = 0; kr < 6; ++kr) {
        f16x8 A[6];
#pragma unroll
        for (int ks = 0; ks < 6; ++ks) A[ks] = WrP[((2 * kr) * 6 + ks) * 64 + l];
        f32x4 c00 = zz, c01 = zz;
#pragma unroll
        for (int ks = 0; ks < 6; ++ks) {
            c00 = MFMA(A[ks], aH[0][ks], c00);
            c01 = MFMA(A[ks], aH[1][ks], c01);
        }
#pragma unroll
        for (int ks = 0; ks < 6; ++ks) A[ks] = WrP[((2 * kr + 1) * 6 + ks) * 64 + l];
        f32x4 c10 = zz, c11 = zz;
#pragma unroll
        for (int ks = 0; ks < 6; ++ks) {
            c10 = MFMA(A[ks], aH[0][ks], c10);
            c11 = MFMA(A[ks], aH[1][ks], c11);
        }
        float4 bA = *(const float4*)(br + 32 * kr + 4 * g4);
        float4 bB = *(const float4*)(br + 32 * kr + 16 + 4 * g4);
#pragma unroll
        for (int rg = 0; rg < 2; ++rg) {
            f32x4 clo = (rg == 0) ? c00 : c01;
            f32x4 chi = (rg == 0) ? c10 : c11;
            f16x8 h = aH[rg][kr];
            float s0 = 1.f / (1.f + __expf(-(clo[0] + bA.x)));
            float s1 = 1.f / (1.f + __expf(-(clo[1] + bA.y)));
            float s2 = 1.f / (1.f + __expf(-(clo[2] + bA.z)));
            float s3 = 1.f / (1.f + __expf(-(clo[3] + bA.w)));
            float s4 = 1.f / (1.f + __expf(-(chi[0] + bB.x)));
            float s5 = 1.f / (1.f + __expf(-(chi[1] + bB.y)));
            float s6 = 1.f / (1.f + __expf(-(chi[2] + bB.z)));
            float s7 = 1.f / (1.f + __expf(-(chi[3] + bB.w)));
            f16x8 o = {(f16)(s0 * (float)h[0]), (f16)(s1 * (float)h[1]),
                       (f16)(s2 * (float)h[2]), (f16)(s3 * (float)h[3]),
                       (f16)(s4 * (float)h[4]), (f16)(s5 * (float)h[5]),
                       (f16)(s6 * (float)h[6]), (f16)(s7 * (float)h[7])};
            if (rg == 0) aR0[kr] = o;
            else         Lr[w][kr][l] = o;      // LDS spill (wave-local)
        }
    }

    // ---- GEMM2 (transposed ONLY): ht[rg][t4] = Wh_t4 @ rh^T ----
    f32x4 ht[2][4];
#pragma unroll
    for (int rg = 0; rg < 2; ++rg)
#pragma unroll
        for (int t4 = 0; t4 < 4; ++t4) ht[rg][t4] = zz;
#pragma unroll
    for (int ks = 0; ks < 6; ++ks) {
        f16x8 Wt[4];
#pragma unroll
        for (int t4 = 0; t4 < 4; ++t4) Wt[t4] = WhP[(t4 * 6 + ks) * 64 + l];
        f16x8 a1 = Lr[w][ks][l];                // LDS reload (wave-local)
#pragma unroll
        for (int t4 = 0; t4 < 4; ++t4) {
            ht[0][t4] = MFMA(Wt[t4], aR0[ks], ht[0][t4]);
            ht[1][t4] = MFMA(Wt[t4], a1, ht[1][t4]);
        }
    }

    // ---- tanh; build aZ in regs; stash hH to Lh for the epilogue ----
    // ht[rg][t4][r] at lane l = hH[row = rg*16+l15][h_col = 16*t4 + 4*g4 + r]
    f16x8 aZ[2][2];
    {
        float4 bh0 = *(const float4*)(bh + 4 * g4);
        float4 bh1 = *(const float4*)(bh + 16 + 4 * g4);
        float4 bh2 = *(const float4*)(bh + 32 + 4 * g4);
        float4 bh3 = *(const float4*)(bh + 48 + 4 * g4);
#pragma unroll
        for (int rg = 0; rg < 2; ++rg) {
            f16x4 th0 = {(f16)tanh_(ht[rg][0][0] + bh0.x), (f16)tanh_(ht[rg][0][1] + bh0.y),
                         (f16)tanh_(ht[rg][0][2] + bh0.z), (f16)tanh_(ht[rg][0][3] + bh0.w)};
            f16x4 th1 = {(f16)tanh_(ht[rg][1][0] + bh1.x), (f16)tanh_(ht[rg][1][1] + bh1.y),
                         (f16)tanh_(ht[rg][1][2] + bh1.z), (f16)tanh_(ht[rg][1][3] + bh1.w)};
            f16x4 th2 = {(f16)tanh_(ht[rg][2][0] + bh2.x), (f16)tanh_(ht[rg][2][1] + bh2.y),
                         (f16)tanh_(ht[rg][2][2] + bh2.z), (f16)tanh_(ht[rg][2][3] + bh2.w)};
            f16x4 th3 = {(f16)tanh_(ht[rg][3][0] + bh3.x), (f16)tanh_(ht[rg][3][1] + bh3.y),
                         (f16)tanh_(ht[rg][3][2] + bh3.z), (f16)tanh_(ht[rg][3][3] + bh3.w)};
            int row = rg * 16 + l15;
            *(f16x4*)&Lh[w][row][4 * g4]      = th0;
            *(f16x4*)&Lh[w][row][16 + 4 * g4] = th1;
            *(f16x4*)&Lh[w][row][32 + 4 * g4] = th2;
            *(f16x4*)&Lh[w][row][48 + 4 * g4] = th3;
            aZ[rg][0] = (f16x8){th0[0], th0[1], th0[2], th0[3],
                                th1[0], th1[1], th1[2], th1[3]};
            aZ[rg][1] = (f16x8){th2[0], th2[1], th2[2], th2[3],
                                th3[0], th3[1], th3[2], th3[3]};
        }
    }

    // ---- GEMM3 (normal) + fused epilogue per 16-col group T ----
#pragma unroll
    for (int T = 0; T < 4; ++T) {
        f32x4 ac[2][4];
#pragma unroll
        for (int g = 0; g < 4; ++g) {
            int nt = g * 4 + T;
            f16x8 bb[8];
#pragma unroll
            for (int ks = 0; ks < 8; ++ks) bb[ks] = WzP[(nt * 8 + ks) * 64 + l];
#pragma unroll
            for (int rg = 0; rg < 2; ++rg) {
                f32x4 a = zz;
                a = MFMA(aZ[rg][0], bb[0], a);
                a = MFMA(aZ[rg][1], bb[1], a);
#pragma unroll
                for (int ks = 2; ks < 8; ++ks) a = MFMA(aH[rg][ks - 2], bb[ks], a);
                ac[rg][g] = a;
            }
        }
        int col = T * 16 + l15;
        float b0 = bz[col], b1 = bz[64 + col], b2 = bz[128 + col], b3 = bz[192 + col];
#pragma unroll
        for (int rg = 0; rg < 2; ++rg)
#pragma unroll
            for (int r = 0; r < 4; ++r) {
                int row = rg * 16 + 4 * g4 + r;
                int i = wbase + row;
                float z0 = ac[rg][0][r] + b0;
                float z1 = ac[rg][1][r] + b1;
                float z2 = ac[rg][2][r] + b2;
                float z3 = ac[rg][3][r] + b3;
                float mx = fmaxf(fmaxf(z0, z1), fmaxf(z2, z3));
                float e0 = __expf(z0 - mx), e1 = __expf(z1 - mx);
                float e2 = __expf(z2 - mx), e3 = __expf(z3 - mx);
                float rs = __frcp_rn(e0 + e1 + e2 + e3);
                float hHv = (float)Lh[w][row][col];
                float hLv = (float)LgL[w][row][col];
                float hRv = (float)LgR[w][row][col];
                float uv  = embC[(size_t)i * 64 + col];     // read-before-write
                embC[(size_t)i * 64 + col] =
                    (e0 * hHv + e1 * hLv + e2 * hRv + e3 * uv) * rs;
            }
    }
}

// ---------------------------------------------------------------------------
extern "C" void kernel_launch(void* const* d_in, const int* in_sizes, int n_in,
                              void* d_out, int out_size, void* d_ws, size_t ws_size,
                              hipStream_t stream) {
    const float* contents = (const float*)d_in[0];
    const int*   children = (const int*)d_in[1];
    const float* Wu = (const float*)d_in[2];
    const float* bu = (const float*)d_in[3];
    const float* Wh = (const float*)d_in[4];
    const float* bh = (const float*)d_in[5];
    const float* Wz = (const float*)d_in[6];
    const float* bz = (const float*)d_in[7];
    const float* Wr = (const float*)d_in[8];
    const float* br = (const float*)d_in[9];
    float* out = (float*)d_out;
    float* ws  = (float*)d_ws;

    float* embEven = ws;                             // N*64 fp32
    f16*   pack    = (f16*)(ws + (size_t)N_DIM * H_DIM);
    const f16x8* WrP = (const f16x8*)pack;
    const f16x8* WhP = (const f16x8*)(pack + NR_PK);
    const f16x8* WzP = (const f16x8*)(pack + NR_PK + NH_PK);

    const int NPK = NR_PK + NH_PK + NZ_PK;
    prep_pack<<<(NPK + 255) / 256, 256, 0, stream>>>(Wr, Wh, Wz, pack);

    int ublocks = (N_DIM * 16 + 255) / 256;   // 12500
    int sblocks = (NTILE + 3) / 4;            // 782 wgs x 4 waves

    u_kernel<<<ublocks, 256, 0, stream>>>(contents, Wu, bu, embEven);

    for (int l = 1; l < L_DIM; ++l) {
        float* cur        = (l & 1) ? out : embEven;
        const float* prev = (l & 1) ? embEven : out;
        u_kernel<<<ublocks, 256, 0, stream>>>(contents + (size_t)l * N_DIM * F_DIM,
                                              Wu, bu, cur);
        step_kernel<<<sblocks, 256, 0, stream>>>(prev, cur,
                                                 children + (size_t)(l - 1) * M_DIM * 2,
                                                 WrP, WhP, WzP, br, bh, bz);
    }
}